// Round 1
// baseline (149.346 us; speedup 1.0000x reference)
//
#include <hip/hip_runtime.h>

// ISTA T=5, LAM=0.1, B=L=4096, K=128.
// R4: single-pass composite-kernel formulation.
//  u = corr(y - corr(y,h), rev(h)). In the interior this is one 255-tap
//  correlation:  u[i] = sum_t G[t]*y[i+t],
//    G[t] = [t in [-63,64]] h[64-t] - ac[|t-1|],  ac[tau]=sum_m h[m]h[m+tau],
//    t in [-126,128].
//  The r-truncation (r==0 outside [0,L)) only affects cols [0,63) and
//  [L-64,L): a small exact two-pass edge kernel overwrites those strips.
//  ISTA closed form (constant u): x_5 = 5*soft(s*u, LAM).

typedef __bf16 bf16;
typedef __bf16 bf16x4 __attribute__((ext_vector_type(4)));
typedef __bf16 bf16x8 __attribute__((ext_vector_type(8)));
typedef float f32x4 __attribute__((ext_vector_type(4)));

#define LC 512      // L-chunk per block (main kernel)
#define PY 792      // y-stage pitch bf16: 1584 B = 396 dw, 396%32=12 -> 2/bank
#define LAM 0.1f

// ---------------- main kernel: single-pass G conv ----------------
// grid 2048: chunk = bid>>8 (8 chunks), bgroup = bid&255 -> all chunks of a
// row-group land on the same XCD (bid%8 == bgroup%8) for halo L2 reuse.
__global__ __launch_bounds__(256) void ista_g(
    const float* __restrict__ y, const float* __restrict__ h,
    const float* __restrict__ step, float* __restrict__ out) {
  __shared__ __align__(16) bf16 ys[16 * PY];   // y, L-positions [-128, LC+144)
  __shared__ __align__(16) bf16 gpad[384];     // G[t] at p = t+144, zero outside
  __shared__ float hs[256];                    // h zero-padded to 256

  const int tid = threadIdx.x;
  const int lane = tid & 63;
  const int li = lane & 15;     // A-row i AND C column b
  const int quad = lane >> 4;
  const int wave = tid >> 6;
  const int bid = blockIdx.x;
  const int chunk0 = (bid >> 8) * LC;
  const int b0 = (bid & 255) * 16;

  {
    float hv = 0.f;
    if (tid < 128) hv = h[tid];
    hs[tid] = hv;
  }

  // ---- stage y (fp32 global -> bf16 LDS): 784 elems = 196 float4 per row ----
  {
    const int rr = tid >> 4;
    const int t = tid & 15;
    const float* yrow = y + (size_t)(b0 + rr) * 4096;
    bf16* dst = ys + rr * PY;
#pragma unroll
    for (int k = 0; k < 13; ++k) {
      int s4 = t + 16 * k;
      if (s4 < 196) {
        int l = chunk0 - 128 + s4 * 4;
        float4 v;
        if (l >= 0 && l <= 4096 - 4) {
          v = *reinterpret_cast<const float4*>(yrow + l);
        } else {
          v.x = ((unsigned)(l + 0) < 4096u) ? yrow[l + 0] : 0.f;
          v.y = ((unsigned)(l + 1) < 4096u) ? yrow[l + 1] : 0.f;
          v.z = ((unsigned)(l + 2) < 4096u) ? yrow[l + 2] : 0.f;
          v.w = ((unsigned)(l + 3) < 4096u) ? yrow[l + 3] : 0.f;
        }
        bf16x4 bv;
        bv[0] = (bf16)v.x; bv[1] = (bf16)v.y; bv[2] = (bf16)v.z; bv[3] = (bf16)v.w;
        *reinterpret_cast<bf16x4*>(dst + s4 * 4) = bv;
      }
    }
  }
  __syncthreads();   // hs + ys ready

  // ---- build gpad: thread tau<128 computes ac[tau] and both taps using it ----
  if (tid < 128) {
    const int tau = tid;
    float ac = 0.f;
#pragma unroll 8
    for (int m = 0; m < 128; ++m) ac += hs[m] * hs[m + tau];  // hs zero-padded
    // t = 1+tau  (p = 145+tau):  h-term h[64-t] = hs[63-tau] for tau<=63
    float g1 = (tau <= 63) ? hs[63 - tau] : 0.f;
    gpad[145 + tau] = (bf16)(g1 - ac);
    if (tau > 0) {
      // t = 1-tau  (p = 145-tau): h-term h[64-t] = hs[63+tau] for tau<=64
      float g2 = (tau <= 64) ? hs[63 + tau] : 0.f;
      gpad[145 - tau] = (bf16)(g2 - ac);
    }
  } else {
    const int r = tid - 128;                    // zero p in [0,18) u [273,384)
    if (r < 18) gpad[r] = (bf16)0.f;
    if (273 + r < 384) gpad[273 + r] = (bf16)0.f;
  }
  __syncthreads();   // gpad ready

  // ---- A-fragments from gpad: A[m=li][k=quad*8+j] = G[d + k - li] ----
  bf16x8 AG[9];
  {
    const int off = 144 + quad * 8 - li;        // + (dd-4)*32 per chunk
#pragma unroll
    for (int dd = 0; dd < 9; ++dd) {
      bf16x8 a;
      const int o = off + (dd - 4) * 32;        // in [1, 296]
#pragma unroll
      for (int j = 0; j < 8; ++j) a[j] = gpad[o + j];
      AG[dd] = a;
    }
  }

  // ---- conv + closed-form epilogue: tiles i0 = 16t, t in [0,32) ----
  const float s = step[0];
  for (int t = wave; t < 32; t += 4) {
    const int i0 = 16 * t;
    f32x4 acc0 = {0.f, 0.f, 0.f, 0.f};
    f32x4 acc1 = {0.f, 0.f, 0.f, 0.f};
    const bf16* brow = ys + li * PY + (i0 + 128) + quad * 8;
#pragma unroll
    for (int dd = 0; dd < 9; dd += 2) {
      bf16x8 b = *reinterpret_cast<const bf16x8*>(brow + (dd - 4) * 32);
      acc0 = __builtin_amdgcn_mfma_f32_16x16x32_bf16(AG[dd], b, acc0, 0, 0, 0);
    }
#pragma unroll
    for (int dd = 1; dd < 9; dd += 2) {
      bf16x8 b = *reinterpret_cast<const bf16x8*>(brow + (dd - 4) * 32);
      acc1 = __builtin_amdgcn_mfma_f32_16x16x32_bf16(AG[dd], b, acc1, 0, 0, 0);
    }
    float4 xv;
#pragma unroll
    for (int e = 0; e < 4; ++e) {
      float su = s * (acc0[e] + acc1[e]);
      float ax = fabsf(su) - LAM;
      ax = ax > 0.f ? ax : 0.f;
      (&xv.x)[e] = 5.f * copysignf(ax, su);
    }
    *reinterpret_cast<float4*>(
        out + (size_t)(b0 + li) * 4096 + chunk0 + i0 + quad * 4) = xv;
  }
}

// ---------------- edge kernel: exact two-pass on 64-col strips ----------------
#define EC 64
#define PYE 360    // 352 needed; 180 dw % 32 = 20 -> 2/bank
#define PRE 216    // 208 needed; 108 dw % 32 = 12 -> 2/bank
__global__ __launch_bounds__(256) void ista_edge(
    const float* __restrict__ y, const float* __restrict__ h,
    const float* __restrict__ step, float* __restrict__ out) {
  __shared__ __align__(16) bf16 ys[16 * PYE];  // y, positions [-128, EC+160)
  __shared__ __align__(16) bf16 rs[16 * PRE];  // -r, positions [-64, EC+80)
  __shared__ __align__(16) bf16 h1p[256], h2p[256];

  const int tid = threadIdx.x;
  const int lane = tid & 63;
  const int li = lane & 15;
  const int quad = lane >> 4;
  const int wave = tid >> 6;
  const int bid = blockIdx.x;
  const int chunk0 = (bid & 1) ? (4096 - EC) : 0;
  const int b0 = (bid >> 1) * 16;

  {  // padded Toeplitz tables: h1p[p]=h[p-64]; h2p[p]=-h[191-p]; zero outside
    const int p = tid;
    int i1 = p - 64;
    h1p[p] = ((unsigned)i1 < 128u) ? (bf16)h[i1] : (bf16)0.f;
    int i2 = 191 - p;
    h2p[p] = ((unsigned)i2 < 128u) ? (bf16)(-h[i2]) : (bf16)0.f;
  }

  // ---- stage y: 352 elems = 88 float4 per row ----
  {
    const int rr = tid >> 4;
    const int t = tid & 15;
    const float* yrow = y + (size_t)(b0 + rr) * 4096;
    bf16* dst = ys + rr * PYE;
#pragma unroll
    for (int k = 0; k < 6; ++k) {
      int s4 = t + 16 * k;
      if (s4 < 88) {
        int l = chunk0 - 128 + s4 * 4;
        float4 v;
        if (l >= 0 && l <= 4096 - 4) {
          v = *reinterpret_cast<const float4*>(yrow + l);
        } else {
          v.x = ((unsigned)(l + 0) < 4096u) ? yrow[l + 0] : 0.f;
          v.y = ((unsigned)(l + 1) < 4096u) ? yrow[l + 1] : 0.f;
          v.z = ((unsigned)(l + 2) < 4096u) ? yrow[l + 2] : 0.f;
          v.w = ((unsigned)(l + 3) < 4096u) ? yrow[l + 3] : 0.f;
        }
        bf16x4 bv;
        bv[0] = (bf16)v.x; bv[1] = (bf16)v.y; bv[2] = (bf16)v.z; bv[3] = (bf16)v.w;
        *reinterpret_cast<bf16x4*>(dst + s4 * 4) = bv;
      }
    }
  }
  __syncthreads();

  // ---- A-fragments from padded tables ----
  bf16x8 A1[5], A2[5];
  {
    const int off = 127 + quad * 8 - li;
#pragma unroll
    for (int dd = 0; dd < 5; ++dd) {
      const int o = off + (dd - 2) * 32;        // in [48, 215]
      bf16x8 a1, a2;
#pragma unroll
      for (int j = 0; j < 8; ++j) { a1[j] = h1p[o + j]; a2[j] = h2p[o + j]; }
      A1[dd] = a1; A2[dd] = a2;
    }
  }

  // ---- conv1: tiles i0 = -64+16t, t in [0,13); emit -r ----
  for (int t = wave; t < 13; t += 4) {
    const int i0 = -64 + 16 * t;
    f32x4 acc;
    {
      bf16x4 yv = *reinterpret_cast<const bf16x4*>(
          ys + li * PYE + (i0 + 128) + quad * 4);
      acc[0] = -(float)yv[0]; acc[1] = -(float)yv[1];
      acc[2] = -(float)yv[2]; acc[3] = -(float)yv[3];
    }
#pragma unroll
    for (int dd = 0; dd < 5; ++dd) {
      bf16x8 b = *reinterpret_cast<const bf16x8*>(
          ys + li * PYE + (i0 + (dd - 2) * 32 + 128) + quad * 8);
      acc = __builtin_amdgcn_mfma_f32_16x16x32_bf16(A1[dd], b, acc, 0, 0, 0);
    }
    bf16x4 rv;
#pragma unroll
    for (int e = 0; e < 4; ++e) {
      int g = chunk0 + i0 + quad * 4 + e;
      float v = ((unsigned)g < 4096u) ? acc[e] : 0.f;   // truncate r
      rv[e] = (bf16)v;
    }
    *reinterpret_cast<bf16x4*>(rs + li * PRE + (i0 + 64) + quad * 4) = rv;
  }
  __syncthreads();

  // ---- conv2 + closed-form epilogue: tiles i0 = 16t, t in [0,4) ----
  const float s = step[0];
  for (int t = wave; t < 4; t += 4) {
    const int i0 = 16 * t;
    f32x4 acc = {0.f, 0.f, 0.f, 0.f};
#pragma unroll
    for (int dd = 0; dd < 5; ++dd) {
      bf16x8 b = *reinterpret_cast<const bf16x8*>(
          rs + li * PRE + (i0 + (dd - 2) * 32 + 64) + quad * 8);
      acc = __builtin_amdgcn_mfma_f32_16x16x32_bf16(A2[dd], b, acc, 0, 0, 0);
    }
    float4 xv;
#pragma unroll
    for (int e = 0; e < 4; ++e) {
      float su = s * acc[e];
      float ax = fabsf(su) - LAM;
      ax = ax > 0.f ? ax : 0.f;
      (&xv.x)[e] = 5.f * copysignf(ax, su);
    }
    *reinterpret_cast<float4*>(
        out + (size_t)(b0 + li) * 4096 + chunk0 + i0 + quad * 4) = xv;
  }
}

extern "C" void kernel_launch(void* const* d_in, const int* in_sizes, int n_in,
                              void* d_out, int out_size, void* d_ws,
                              size_t ws_size, hipStream_t stream) {
  const float* y = (const float*)d_in[0];
  const float* h = (const float*)d_in[1];
  const float* s = (const float*)d_in[2];
  float* out = (float*)d_out;
  // main: interior via composite 255-tap kernel (writes all cols; edge cols
  // are wrong there and overwritten by ista_edge afterwards, stream-ordered).
  ista_g<<<dim3(8 * 256), dim3(256), 0, stream>>>(y, h, s, out);
  // edges: exact truncation-aware two-pass on cols [0,64) and [4032,4096).
  ista_edge<<<dim3(2 * 256), dim3(256), 0, stream>>>(y, h, s, out);
}

// Round 2
// 133.100 us; speedup vs baseline: 1.1221x; 1.1221x over previous
//
#include <hip/hip_runtime.h>

// ISTA T=5, LAM=0.1, B=L=4096, K=128.
// R5: prep-kernel + fused single-launch composite formulation.
//  u = corr(y - corr(y,h), rev(h)) == (interior) one 255-tap correlation
//    G[t] = [t in [-63,64]] h[64-t] - ac[|t-1|],  ac[tau]=sum_m h[m]h[m+tau].
//  r-truncation only affects cols [0,64) u [L-64,L): exact two-pass edge
//  blocks (same launch, disjoint output columns) fix those strips.
//  ISTA closed form (constant u): x_5 = 5*soft(s*u, LAM).
//  ista_prep (1 block) builds lane-layout MFMA A-fragment tables in d_ws:
//  main blocks skip the per-block autocorr chain + one barrier entirely.

typedef __bf16 bf16;
typedef __bf16 bf16x4 __attribute__((ext_vector_type(4)));
typedef __bf16 bf16x8 __attribute__((ext_vector_type(8)));
typedef float f32x4 __attribute__((ext_vector_type(4)));

#define LC 512      // L-chunk per interior block
#define PY 824      // y-stage pitch bf16: 1648 B = 412 dw, 412%32=28 -> 2/bank
#define LAM 0.1f
// ws layout in bf16 elems (16-B aligned fragments):
#define WS_AG 0      // AG frag:  lane*128 + dd*8, dd<9
#define WS_A1 8192   // A1e frag: lane*64  + dd*8, dd<5
#define WS_A2 12288  // A2e frag: lane*64  + dd*8, dd<5
// edge-path LDS partition (carved from buf):
#define PYE 360      // y strip pitch (352 needed)
#define PRE 216      // r strip pitch (208 needed)

// ---------------- prep: G + lane-layout A-fragment tables ----------------
__global__ __launch_bounds__(256) void ista_prep(const float* __restrict__ h,
                                                 bf16* __restrict__ ws) {
  __shared__ float hs[256];    // h zero-padded
  __shared__ float acp[256];   // autocorr partials
  __shared__ bf16 gp[384];     // G[t] at p=t+144, zero outside
  const int tid = threadIdx.x;
  hs[tid] = (tid < 128) ? h[tid] : 0.f;
  gp[tid] = (bf16)0.f;
  if (tid < 128) gp[256 + tid] = (bf16)0.f;
  __syncthreads();
  const int tau = tid & 127;
  {  // split ac over two halves x 4 accumulators (short dep chains)
    const int m0 = (tid >> 7) * 64;
    float p0 = 0.f, p1 = 0.f, p2 = 0.f, p3 = 0.f;
    for (int m = m0; m < m0 + 64; m += 4) {
      p0 += hs[m] * hs[m + tau];     p1 += hs[m + 1] * hs[m + 1 + tau];
      p2 += hs[m + 2] * hs[m + 2 + tau]; p3 += hs[m + 3] * hs[m + 3 + tau];
    }
    acp[tid] = (p0 + p1) + (p2 + p3);
  }
  __syncthreads();
  if (tid < 128) {
    float ac = acp[tid] + acp[tid + 128];
    float g1 = (tau <= 63) ? hs[63 - tau] : 0.f;
    gp[145 + tau] = (bf16)(g1 - ac);
    if (tau > 0) {
      float g2 = (tau <= 64) ? hs[63 + tau] : 0.f;
      gp[145 - tau] = (bf16)(g2 - ac);
    }
  }
  __syncthreads();
  // AG lane-layout: A[m=li][k=quad*8+j] = G[144 + quad*8 - li + (dd-4)*32 + j]
  for (int i = tid; i < 1024; i += 256) {
    const int l = i >> 4, dd = i & 15;
    if (dd < 9) {
      const int o = 144 + (l >> 4) * 8 - (l & 15) + (dd - 4) * 32;
      bf16x8 a;
#pragma unroll
      for (int j = 0; j < 8; ++j) a[j] = gp[o + j];
      *reinterpret_cast<bf16x8*>(ws + WS_AG + l * 128 + dd * 8) = a;
    }
  }
  // edge Toeplitz tables: h1p[p]=h[p-64], h2p[p]=-h[191-p] (zero outside)
  for (int i = tid; i < 512; i += 256) {
    const int l = i >> 3, dd = i & 7;
    if (dd < 5) {
      const int o = 127 + (l >> 4) * 8 - (l & 15) + (dd - 2) * 32;
      bf16x8 a1, a2;
#pragma unroll
      for (int j = 0; j < 8; ++j) {
        int p = o + j;
        int i1 = p - 64;
        a1[j] = ((unsigned)i1 < 128u) ? (bf16)hs[i1] : (bf16)0.f;
        int i2 = 191 - p;
        a2[j] = ((unsigned)i2 < 128u) ? (bf16)(-hs[i2]) : (bf16)0.f;
      }
      *reinterpret_cast<bf16x8*>(ws + WS_A1 + l * 64 + dd * 8) = a1;
      *reinterpret_cast<bf16x8*>(ws + WS_A2 + l * 64 + dd * 8) = a2;
    }
  }
}

// ---------------- fused main: interior composite + edge two-pass ----------
__global__ __launch_bounds__(256) void ista_fused(
    const float* __restrict__ y, const bf16* __restrict__ ws,
    const float* __restrict__ step, float* __restrict__ out) {
  __shared__ __align__(16) bf16 buf[16 * PY];   // 26368 B
  const int tid = threadIdx.x;
  const int lane = tid & 63;
  const int li = lane & 15;     // A-row i AND C column b
  const int quad = lane >> 4;
  const int wave = tid >> 6;
  const int bid = blockIdx.x;
  const float s = step[0];

  if (bid < 2048) {
    // ---------------- interior: single-pass G conv ----------------
    // chunk = bid>>8 -> all chunks of a row-group share an XCD (bid%8 const).
    const int chunk0 = (bid >> 8) * LC;
    const int b0 = (bid & 255) * 16;

    // A-fragments from ws (global, L1-broadcast; overlaps staging)
    bf16x8 AG[9];
#pragma unroll
    for (int dd = 0; dd < 9; ++dd)
      AG[dd] = *reinterpret_cast<const bf16x8*>(ws + WS_AG + lane * 128 + dd * 8);

    // stage y (fp32 -> bf16 LDS): 800 elems = 200 float4 per row
    {
      const int rr = tid >> 4;
      const int t = tid & 15;
      const float* yrow = y + (size_t)(b0 + rr) * 4096;
      bf16* dst = buf + rr * PY;
      if (chunk0 != 0 && chunk0 != 3584) {   // fully in-bounds fast path
#pragma unroll
        for (int k = 0; k < 13; ++k) {
          int s4 = t + 16 * k;
          if (s4 < 200) {
            float4 v = *reinterpret_cast<const float4*>(yrow + chunk0 - 128 + s4 * 4);
            bf16x4 bv;
            bv[0] = (bf16)v.x; bv[1] = (bf16)v.y; bv[2] = (bf16)v.z; bv[3] = (bf16)v.w;
            *reinterpret_cast<bf16x4*>(dst + s4 * 4) = bv;
          }
        }
      } else {
#pragma unroll
        for (int k = 0; k < 13; ++k) {
          int s4 = t + 16 * k;
          if (s4 < 200) {
            int l = chunk0 - 128 + s4 * 4;
            float4 v;
            if (l >= 0 && l <= 4096 - 4) {
              v = *reinterpret_cast<const float4*>(yrow + l);
            } else {
              v.x = ((unsigned)(l + 0) < 4096u) ? yrow[l + 0] : 0.f;
              v.y = ((unsigned)(l + 1) < 4096u) ? yrow[l + 1] : 0.f;
              v.z = ((unsigned)(l + 2) < 4096u) ? yrow[l + 2] : 0.f;
              v.w = ((unsigned)(l + 3) < 4096u) ? yrow[l + 3] : 0.f;
            }
            bf16x4 bv;
            bv[0] = (bf16)v.x; bv[1] = (bf16)v.y; bv[2] = (bf16)v.z; bv[3] = (bf16)v.w;
            *reinterpret_cast<bf16x4*>(dst + s4 * 4) = bv;
          }
        }
      }
    }
    __syncthreads();

    // 8 tiles per wave (i0 = 16*wave + 64*k); sliding 9-window B registers,
    // step 64 = 2 windows -> only 2 new ds_read_b128 per tile.
    const bf16* brow = buf + li * PY + 128 + quad * 8;
    const int iw = 16 * wave;
    bf16x8 B[9];
#pragma unroll
    for (int dd = 0; dd < 9; ++dd)
      B[dd] = *reinterpret_cast<const bf16x8*>(brow + iw + (dd - 4) * 32);
    float* orow = out + (size_t)(b0 + li) * 4096 + chunk0 + iw + quad * 4;
#pragma unroll
    for (int k = 0; k < 8; ++k) {
      f32x4 acc0 = {0.f, 0.f, 0.f, 0.f};
      f32x4 acc1 = {0.f, 0.f, 0.f, 0.f};
      acc0 = __builtin_amdgcn_mfma_f32_16x16x32_bf16(AG[0], B[0], acc0, 0, 0, 0);
      acc1 = __builtin_amdgcn_mfma_f32_16x16x32_bf16(AG[1], B[1], acc1, 0, 0, 0);
      acc0 = __builtin_amdgcn_mfma_f32_16x16x32_bf16(AG[2], B[2], acc0, 0, 0, 0);
      acc1 = __builtin_amdgcn_mfma_f32_16x16x32_bf16(AG[3], B[3], acc1, 0, 0, 0);
      acc0 = __builtin_amdgcn_mfma_f32_16x16x32_bf16(AG[4], B[4], acc0, 0, 0, 0);
      acc1 = __builtin_amdgcn_mfma_f32_16x16x32_bf16(AG[5], B[5], acc1, 0, 0, 0);
      acc0 = __builtin_amdgcn_mfma_f32_16x16x32_bf16(AG[6], B[6], acc0, 0, 0, 0);
      acc1 = __builtin_amdgcn_mfma_f32_16x16x32_bf16(AG[7], B[7], acc1, 0, 0, 0);
      acc0 = __builtin_amdgcn_mfma_f32_16x16x32_bf16(AG[8], B[8], acc0, 0, 0, 0);
      const int gc0 = chunk0 + iw + 64 * k;
      if (gc0 >= 64 && gc0 < 4032) {   // edge strips owned by edge blocks
        float4 xv;
#pragma unroll
        for (int e = 0; e < 4; ++e) {
          float su = s * (acc0[e] + acc1[e]);
          float ax = fabsf(su) - LAM;
          ax = ax > 0.f ? ax : 0.f;
          (&xv.x)[e] = 5.f * copysignf(ax, su);
        }
        *reinterpret_cast<float4*>(orow + 64 * k) = xv;
      }
      if (k < 7) {
#pragma unroll
        for (int r = 0; r < 7; ++r) B[r] = B[r + 2];
        B[7] = *reinterpret_cast<const bf16x8*>(brow + iw + 64 * (k + 1) + 96);
        B[8] = *reinterpret_cast<const bf16x8*>(brow + iw + 64 * (k + 1) + 128);
      }
    }
  } else {
    // ---------------- edge: exact two-pass on 64-col strips ----------------
    const int eid = bid - 2048;
    const int chunk0 = (eid & 1) ? (4096 - 64) : 0;
    const int b0 = (eid >> 1) * 16;
    bf16* ys = buf;                 // 16 x PYE, positions [-128, 224)
    bf16* rs = buf + 16 * PYE;      // 16 x PRE, -r at positions [-64, 144)

    bf16x8 A1[5], A2[5];
#pragma unroll
    for (int dd = 0; dd < 5; ++dd) {
      A1[dd] = *reinterpret_cast<const bf16x8*>(ws + WS_A1 + lane * 64 + dd * 8);
      A2[dd] = *reinterpret_cast<const bf16x8*>(ws + WS_A2 + lane * 64 + dd * 8);
    }

    {  // stage y: 352 elems = 88 float4 per row (guarded)
      const int rr = tid >> 4;
      const int t = tid & 15;
      const float* yrow = y + (size_t)(b0 + rr) * 4096;
      bf16* dst = ys + rr * PYE;
#pragma unroll
      for (int k = 0; k < 6; ++k) {
        int s4 = t + 16 * k;
        if (s4 < 88) {
          int l = chunk0 - 128 + s4 * 4;
          float4 v;
          if (l >= 0 && l <= 4096 - 4) {
            v = *reinterpret_cast<const float4*>(yrow + l);
          } else {
            v.x = ((unsigned)(l + 0) < 4096u) ? yrow[l + 0] : 0.f;
            v.y = ((unsigned)(l + 1) < 4096u) ? yrow[l + 1] : 0.f;
            v.z = ((unsigned)(l + 2) < 4096u) ? yrow[l + 2] : 0.f;
            v.w = ((unsigned)(l + 3) < 4096u) ? yrow[l + 3] : 0.f;
          }
          bf16x4 bv;
          bv[0] = (bf16)v.x; bv[1] = (bf16)v.y; bv[2] = (bf16)v.z; bv[3] = (bf16)v.w;
          *reinterpret_cast<bf16x4*>(dst + s4 * 4) = bv;
        }
      }
    }
    __syncthreads();

    // conv1: tiles i0 = -64+16t, t in [0,13); emit -r (truncated to [0,L))
    for (int t = wave; t < 13; t += 4) {
      const int i0 = -64 + 16 * t;
      f32x4 acc;
      {
        bf16x4 yv = *reinterpret_cast<const bf16x4*>(
            ys + li * PYE + (i0 + 128) + quad * 4);
        acc[0] = -(float)yv[0]; acc[1] = -(float)yv[1];
        acc[2] = -(float)yv[2]; acc[3] = -(float)yv[3];
      }
#pragma unroll
      for (int dd = 0; dd < 5; ++dd) {
        bf16x8 b = *reinterpret_cast<const bf16x8*>(
            ys + li * PYE + (i0 + (dd - 2) * 32 + 128) + quad * 8);
        acc = __builtin_amdgcn_mfma_f32_16x16x32_bf16(A1[dd], b, acc, 0, 0, 0);
      }
      bf16x4 rv;
#pragma unroll
      for (int e = 0; e < 4; ++e) {
        int g = chunk0 + i0 + quad * 4 + e;
        float v = ((unsigned)g < 4096u) ? acc[e] : 0.f;
        rv[e] = (bf16)v;
      }
      *reinterpret_cast<bf16x4*>(rs + li * PRE + (i0 + 64) + quad * 4) = rv;
    }
    __syncthreads();

    // conv2 + closed-form epilogue: 4 tiles, one per wave
    {
      const int i0 = 16 * wave;
      f32x4 acc = {0.f, 0.f, 0.f, 0.f};
#pragma unroll
      for (int dd = 0; dd < 5; ++dd) {
        bf16x8 b = *reinterpret_cast<const bf16x8*>(
            rs + li * PRE + (i0 + (dd - 2) * 32 + 64) + quad * 8);
        acc = __builtin_amdgcn_mfma_f32_16x16x32_bf16(A2[dd], b, acc, 0, 0, 0);
      }
      float4 xv;
#pragma unroll
      for (int e = 0; e < 4; ++e) {
        float su = s * acc[e];
        float ax = fabsf(su) - LAM;
        ax = ax > 0.f ? ax : 0.f;
        (&xv.x)[e] = 5.f * copysignf(ax, su);
      }
      *reinterpret_cast<float4*>(
          out + (size_t)(b0 + li) * 4096 + chunk0 + i0 + quad * 4) = xv;
    }
  }
}

extern "C" void kernel_launch(void* const* d_in, const int* in_sizes, int n_in,
                              void* d_out, int out_size, void* d_ws,
                              size_t ws_size, hipStream_t stream) {
  const float* y = (const float*)d_in[0];
  const float* h = (const float*)d_in[1];
  const float* s = (const float*)d_in[2];
  float* out = (float*)d_out;
  bf16* ws = (bf16*)d_ws;   // 32 KB used
  ista_prep<<<dim3(1), dim3(256), 0, stream>>>(h, ws);
  // 2048 interior blocks (cols [64,4032)) + 512 edge blocks (cols [0,64) and
  // [4032,4096)) — disjoint output columns, single launch, stream-ordered
  // after prep.
  ista_fused<<<dim3(2048 + 512), dim3(256), 0, stream>>>(y, ws, s, out);
}